// Round 2
// baseline (1665.163 us; speedup 1.0000x reference)
//
#include <hip/hip_runtime.h>

#define NB 128
#define NL 256
#define NH 512
#define NMAX 256

typedef __attribute__((ext_vector_type(8))) short s8v;
typedef __attribute__((ext_vector_type(4))) float f4v;

struct Params {
  const int* widx;                 // (B, L) int32
  const float* emb;                // (VOCAB, H) f32
  const float* bias[5];            // each (H,) f32: i, fl, fr, o, c
  const unsigned short* wbf;       // ws: 10 x (H,H) bf16, order [gate][side]
  float* out;                      // (B, 256, H) f32
  float* fh;                       // (B, H) forest_h
  float* fc;                       // (B, H) forest_c
  unsigned short* cws;             // ws: (B, 255, H) bf16 internal-node c
};

struct PrepParams {
  const float* src[10];            // U_i_l, U_i_r, U_fl_l, U_fl_r, U_fr_l, U_fr_r, U_o_l, U_o_r, U_c_l, U_c_r
  unsigned short* dst;
};

__device__ __forceinline__ float bf2f(unsigned short u) {
  union { unsigned int i; float f; } v;
  v.i = ((unsigned int)u) << 16;
  return v.f;
}
__device__ __forceinline__ unsigned short f2bf(float f) {
  union { float f; unsigned int i; } v;
  v.f = f;
  unsigned int x = v.i;
  x += 0x7fffu + ((x >> 16) & 1u);   // RNE
  return (unsigned short)(x >> 16);
}
__device__ __forceinline__ s8v cvt8(const float* src) {
  f4v x0 = *(const f4v*)src;
  f4v x1 = *(const f4v*)(src + 4);
  s8v r;
  r[0] = (short)f2bf(x0[0]); r[1] = (short)f2bf(x0[1]);
  r[2] = (short)f2bf(x0[2]); r[3] = (short)f2bf(x0[3]);
  r[4] = (short)f2bf(x1[0]); r[5] = (short)f2bf(x1[1]);
  r[6] = (short)f2bf(x1[2]); r[7] = (short)f2bf(x1[3]);
  return r;
}
__device__ __forceinline__ float sigf(float x) {
  return 1.f / (1.f + __expf(-x));
}

// Convert the 10 (H,H) f32 weight matrices to bf16 in ws.
__global__ __launch_bounds__(256) void prep_weights(PrepParams pp) {
  int gid = blockIdx.x * 256 + threadIdx.x;        // one 8-elem chunk each
  int mat = gid >> 15;                              // 262144/8 = 32768 chunks per matrix
  int off = (gid & 32767) * 8;
  const float* s = pp.src[mat] + off;
  *(s8v*)(pp.dst + mat * NH * NH + off) = cvt8(s);
}

// Post-order position of internal node (k, j): pos = (j+1)*2^k - 2 - popcount(j).
// Output column = pos + 1 (column 0 duplicates node (1,0)).

template<int LEVEL>
__global__ __launch_bounds__(256, 2)
void lstm_level(Params p) {
  constexpr int NK = NL >> LEVEL;      // nodes per batch at this level
  constexpr int LOGNK = 8 - LEVEL;
  const int tid = threadIdx.x;
  const int wave = tid >> 6;
  const int lane = tid & 63;
  const int lhi = lane >> 4;
  const int llo = lane & 15;
  const int mbase = blockIdx.x * 128 + wave * 32;  // 4 waves x 32 rows
  const int ht = blockIdx.y;                       // 64-wide hdim tile

  // ---- A-fragment row base pointers (A layout: row = llo, k = lhi*8 + i) ----
  const float* aptr[2][2];  // [fm][half: 0=left child, 1=right child]
#pragma unroll
  for (int fm = 0; fm < 2; ++fm) {
    int m = mbase + fm * 16 + llo;
    int b = m >> LOGNK;
    int j = m & (NK - 1);
    if constexpr (LEVEL == 1) {
      aptr[fm][0] = p.emb + p.widx[b * NL + 2 * j] * NH;
      aptr[fm][1] = p.emb + p.widx[b * NL + 2 * j + 1] * NH;
    } else {
      // children are internal nodes of level LEVEL-1, indices 2j, 2j+1
      int cl = (((2 * j + 1) << (LEVEL - 1)) - 2 - __popc(j)) + 1;          // popc(2j)=popc(j)
      int cr = (((2 * j + 2) << (LEVEL - 1)) - 2 - (__popc(j) + 1)) + 1;    // popc(2j+1)=popc(j)+1
      aptr[fm][0] = p.out + (b * NMAX + cl) * NH;
      aptr[fm][1] = p.out + (b * NMAX + cr) * NH;
    }
  }

  // ---- B (weight) row offsets: W row = out-hdim (lane llo), K-contiguous ----
  int rowoff[4];
#pragma unroll
  for (int fn = 0; fn < 4; ++fn)
    rowoff[fn] = (ht * 64 + fn * 16 + llo) * NH + lhi * 8;
  const int aoff = lhi * 8;

  f4v acc[5][2][4];
#pragma unroll
  for (int g = 0; g < 5; ++g)
#pragma unroll
    for (int fm = 0; fm < 2; ++fm)
#pragma unroll
      for (int fn = 0; fn < 4; ++fn)
        acc[g][fm][fn] = (f4v){0.f, 0.f, 0.f, 0.f};

  // ---- K loop: half 0 -> left child & U*_l, half 1 -> right child & U*_r ----
#pragma unroll
  for (int half = 0; half < 2; ++half) {
    const float* a0p = aptr[0][half] + aoff;
    const float* a1p = aptr[1][half] + aoff;
    const unsigned short* up[5];
#pragma unroll
    for (int g = 0; g < 5; ++g) up[g] = p.wbf + (2 * g + half) * NH * NH;
#pragma unroll 2
    for (int ko = 0; ko < 512; ko += 32) {
      s8v a0 = cvt8(a0p + ko);
      s8v a1 = cvt8(a1p + ko);
#pragma unroll
      for (int g = 0; g < 5; ++g) {
#pragma unroll
        for (int fn = 0; fn < 4; ++fn) {
          s8v bf = *(const s8v*)(up[g] + rowoff[fn] + ko);
          acc[g][0][fn] = __builtin_amdgcn_mfma_f32_16x16x32_bf16(a0, bf, acc[g][0][fn], 0, 0, 0);
          acc[g][1][fn] = __builtin_amdgcn_mfma_f32_16x16x32_bf16(a1, bf, acc[g][1][fn], 0, 0, 0);
        }
      }
    }
  }

  // ---- Epilogue: gates. C/D layout: col = llo (hdim), row = lhi*4 + reg ----
  float bb[5][4];
#pragma unroll
  for (int g = 0; g < 5; ++g)
#pragma unroll
    for (int fn = 0; fn < 4; ++fn)
      bb[g][fn] = p.bias[g][ht * 64 + fn * 16 + llo];

#pragma unroll
  for (int fm = 0; fm < 2; ++fm) {
#pragma unroll
    for (int jj = 0; jj < 4; ++jj) {
      int m = mbase + fm * 16 + lhi * 4 + jj;
      int b = m >> LOGNK;
      int j = m & (NK - 1);
      int nlm = (NL - (NL >> (LEVEL - 1))) + j;                  // level-major node idx
      int colout = (((j + 1) << LEVEL) - 2 - __popc(j)) + 1;     // out column
      float* hrow = p.out + (b * NMAX + colout) * NH;
      unsigned short* crow = p.cws + (b * 255 + nlm) * NH;
      const unsigned short* clrow = nullptr;
      const unsigned short* crrow = nullptr;
      if constexpr (LEVEL > 1) {
        int offc = NL - (NL >> (LEVEL - 2));                     // OFF[LEVEL-1]
        clrow = p.cws + (b * 255 + offc + 2 * j) * NH;
        crrow = p.cws + (b * 255 + offc + 2 * j + 1) * NH;
      }
#pragma unroll
      for (int fn = 0; fn < 4; ++fn) {
        int hd = ht * 64 + fn * 16 + llo;
        float zi  = acc[0][fm][fn][jj] + bb[0][fn];
        float zfl = acc[1][fm][fn][jj] + bb[1][fn];
        float zfr = acc[2][fm][fn][jj] + bb[2][fn];
        float zo  = acc[3][fm][fn][jj] + bb[3][fn];
        float zc  = acc[4][fm][fn][jj] + bb[4][fn];
        float cl, cr;
        if constexpr (LEVEL == 1) { cl = 0.5f; cr = 0.5f; }
        else { cl = bf2f(clrow[hd]); cr = bf2f(crrow[hd]); }
        float cnew = sigf(zi) * tanhf(zc) + sigf(zfl) * cl + sigf(zfr) * cr;
        float hnew = sigf(zo) * tanhf(cnew);
        hrow[hd] = hnew;
        crow[hd] = f2bf(cnew);
        if (LEVEL == 1 && j == 0) p.out[b * NMAX * NH + hd] = hnew;  // POST[0] dup, col 0
        if (LEVEL == 8) { p.fh[b * NH + hd] = hnew; p.fc[b * NH + hd] = cnew; }
      }
    }
  }
}

extern "C" void kernel_launch(void* const* d_in, const int* in_sizes, int n_in,
                              void* d_out, int out_size, void* d_ws, size_t ws_size,
                              hipStream_t stream) {
  PrepParams pp;
  for (int i = 0; i < 10; ++i) pp.src[i] = (const float*)d_in[2 + i];
  pp.dst = (unsigned short*)d_ws;

  Params p;
  p.widx = (const int*)d_in[0];
  p.emb  = (const float*)d_in[1];
  for (int g = 0; g < 5; ++g) p.bias[g] = (const float*)d_in[12 + g];
  p.wbf  = (const unsigned short*)d_ws;
  p.out  = (float*)d_out;
  p.fh   = p.out + (size_t)NB * NMAX * NH;
  p.fc   = p.fh + NB * NH;
  p.cws  = (unsigned short*)d_ws + (size_t)10 * NH * NH;  // after bf16 weights

  dim3 blk(256);
  prep_weights<<<dim3(1280), blk, 0, stream>>>(pp);        // 10*512*512/8/256
  lstm_level<1><<<dim3(128, 8), blk, 0, stream>>>(p);
  lstm_level<2><<<dim3(64, 8),  blk, 0, stream>>>(p);
  lstm_level<3><<<dim3(32, 8),  blk, 0, stream>>>(p);
  lstm_level<4><<<dim3(16, 8),  blk, 0, stream>>>(p);
  lstm_level<5><<<dim3(8, 8),   blk, 0, stream>>>(p);
  lstm_level<6><<<dim3(4, 8),   blk, 0, stream>>>(p);
  lstm_level<7><<<dim3(2, 8),   blk, 0, stream>>>(p);
  lstm_level<8><<<dim3(1, 8),   blk, 0, stream>>>(p);
}

// Round 3
// 667.752 us; speedup vs baseline: 2.4937x; 2.4937x over previous
//
#include <hip/hip_runtime.h>

#define NB 128
#define NL 256
#define NH 512
#define NMAX 256

typedef __attribute__((ext_vector_type(8))) short s8v;
typedef __attribute__((ext_vector_type(4))) float f4v;

struct Params {
  const int* widx;                 // (B, L) int32
  const float* emb;                // (VOCAB, H) f32
  const float* bias[5];            // each (H,) f32: i, fl, fr, o, c
  const unsigned short* wbf;       // ws: 10 x (H,H) bf16, order [gate][side]
  float* out;                      // (B, 256, H) f32
  float* fh;                       // (B, H) forest_h
  float* fc;                       // (B, H) forest_c
  unsigned short* cws;             // ws: (B, 255, H) bf16 internal-node c
};

struct PrepParams {
  const float* src[10];
  unsigned short* dst;
};

__device__ __forceinline__ float bf2f(unsigned short u) {
  union { unsigned int i; float f; } v;
  v.i = ((unsigned int)u) << 16;
  return v.f;
}
__device__ __forceinline__ unsigned short f2bf(float f) {
  union { float f; unsigned int i; } v;
  v.f = f;
  unsigned int x = v.i;
  x += 0x7fffu + ((x >> 16) & 1u);   // RNE
  return (unsigned short)(x >> 16);
}
__device__ __forceinline__ s8v pack8(f4v a, f4v b) {
  s8v r;
  r[0] = (short)f2bf(a[0]); r[1] = (short)f2bf(a[1]);
  r[2] = (short)f2bf(a[2]); r[3] = (short)f2bf(a[3]);
  r[4] = (short)f2bf(b[0]); r[5] = (short)f2bf(b[1]);
  r[6] = (short)f2bf(b[2]); r[7] = (short)f2bf(b[3]);
  return r;
}
__device__ __forceinline__ float sigf(float x) {
  return 1.f / (1.f + __expf(-x));
}
__device__ __forceinline__ void glds16(const void* g, void* l) {
  __builtin_amdgcn_global_load_lds(
      (const __attribute__((address_space(1))) unsigned int*)g,
      (__attribute__((address_space(3))) unsigned int*)l, 16, 0, 0);
}

// Convert the 10 (H,H) f32 weight matrices to bf16 in ws.
__global__ __launch_bounds__(256) void prep_weights(PrepParams pp) {
  int gid = blockIdx.x * 256 + threadIdx.x;
  int mat = gid >> 15;                       // 262144/8 = 32768 chunks per matrix
  int off = (gid & 32767) * 8;
  const float* s = pp.src[mat] + off;
  f4v x0 = *(const f4v*)s;
  f4v x1 = *(const f4v*)(s + 4);
  *(s8v*)(pp.dst + (size_t)mat * NH * NH + off) = pack8(x0, x1);
}

// Post-order position of internal node (k, j): pos = (j+1)*2^k - 2 - popcount(j).
// Output column = pos + 1 (column 0 duplicates node (1,0)).
//
// GEMM geometry per block: BM=256 rows x (5 gates x 64 hd) x K=1024 (512 left | 512 right).
// 8 waves = 4 wrow x 2 wcol; wave tile = 64 rows x 5 gates x 32 hd. BK=32, double-buffered.
// LDS: A[2][256][64B] @0, B[2][320][64B] @32768.  XOR swizzle: chunk ^= (row>>1)&3.

template<int LEVEL>
__global__ __launch_bounds__(512, 2)
void lstm_level(Params p) {
  constexpr int NK = NL >> LEVEL;
  constexpr int LOGNK = 8 - LEVEL;
  constexpr int M = NB * NK;
  __shared__ __align__(16) unsigned char lds[73728];

  const int tid = threadIdx.x;
  const int wid = tid >> 6;
  const int lane = tid & 63;
  const int lhi = lane >> 4, llo = lane & 15;
  const int wr = wid >> 1, wc = wid & 1;
  const int bm = blockIdx.x, ht = blockIdx.y;

  // ---------- A staging assignment: one row + one k-half per thread ----------
  const int ar = tid & 255;          // LDS tile row
  const int kh = tid >> 8;           // which 16-float half of the 32-k window
  int am = bm * 256 + ar; if (am > M - 1) am = M - 1;
  const float *aL, *aR;
  {
    int b = am >> LOGNK, j = am & (NK - 1);
    if constexpr (LEVEL == 1) {
      aL = p.emb + (size_t)p.widx[b * NL + 2 * j] * NH;
      aR = p.emb + (size_t)p.widx[b * NL + 2 * j + 1] * NH;
    } else {
      int cl = (((2 * j + 1) << (LEVEL - 1)) - 2 - __popc(j)) + 1;
      int cr = (((2 * j + 2) << (LEVEL - 1)) - 2 - (__popc(j) + 1)) + 1;
      aL = p.out + ((size_t)b * NMAX + cl) * NH;
      aR = p.out + ((size_t)b * NMAX + cr) * NH;
    }
  }
  const int aswz = (ar >> 1) & 3;
  const int adst0 = ar * 64 + (((2 * kh) ^ aswz) << 4);
  const int adst1 = ar * 64 + (((2 * kh + 1) ^ aswz) << 4);

  // ---------- fragment LDS byte offsets (swizzled reads) ----------
  int aoff[4];
#pragma unroll
  for (int fm = 0; fm < 4; ++fm) {
    int r = wr * 64 + fm * 16 + llo;
    aoff[fm] = r * 64 + ((lhi ^ ((r >> 1) & 3)) << 4);
  }
  int boff[10];
#pragma unroll
  for (int g = 0; g < 5; ++g)
#pragma unroll
    for (int fnl = 0; fnl < 2; ++fnl) {
      int r = g * 64 + wc * 32 + fnl * 16 + llo;
      boff[g * 2 + fnl] = r * 64 + ((lhi ^ ((r >> 1) & 3)) << 4);
    }

  // ---------- B staging: global_load_lds, pre-swizzled global source ----------
  auto stageB = [&](int buf, int tt) {
    const int half = tt >> 4, kk = tt & 15;
    for (int i = wid; i < 20; i += 8) {           // 20 x 16-row groups
      int g = i >> 2;
      int r = i * 16 + (lane >> 2);               // tile row 0..319
      int ck = (lane & 3) ^ ((r >> 1) & 3);       // pre-swizzled source chunk
      const unsigned short* src = p.wbf
          + ((size_t)(2 * g + half) * NH + (size_t)(ht * 64 + (r & 63))) * NH
          + kk * 32 + ck * 8;
      glds16(src, lds + 32768 + buf * 20480 + i * 1024);
    }
  };

  f4v acc[5][4][2];
#pragma unroll
  for (int g = 0; g < 5; ++g)
#pragma unroll
    for (int fm = 0; fm < 4; ++fm)
#pragma unroll
      for (int fnl = 0; fnl < 2; ++fnl)
        acc[g][fm][fnl] = (f4v){0.f, 0.f, 0.f, 0.f};

  // ---------- prologue: stage t=0 into buffer 0 ----------
  f4v x0, x1, x2, x3;
  {
    const float* s = aL + kh * 16;
    x0 = *(const f4v*)s;       x1 = *(const f4v*)(s + 4);
    x2 = *(const f4v*)(s + 8); x3 = *(const f4v*)(s + 12);
  }
  stageB(0, 0);
  *(s8v*)(lds + adst0) = pack8(x0, x1);
  *(s8v*)(lds + adst1) = pack8(x2, x3);
  __syncthreads();

  // ---------- main K loop: 32 steps of BK=32 (16 left-child, 16 right) ----------
  for (int t = 0; t < 32; ++t) {
    const int cur = t & 1, nxt = cur ^ 1;
    const bool have = (t + 1) < 32;
    if (have) {
      const float* s = ((t + 1) < 16 ? aL : aR) + ((t + 1) & 15) * 32 + kh * 16;
      x0 = *(const f4v*)s;       x1 = *(const f4v*)(s + 4);
      x2 = *(const f4v*)(s + 8); x3 = *(const f4v*)(s + 12);
      stageB(nxt, t + 1);
    }
    const unsigned char* Ab = lds + cur * 16384;
    const unsigned char* Bb = lds + 32768 + cur * 20480;
    s8v af[4], bv[10];
#pragma unroll
    for (int fm = 0; fm < 4; ++fm) af[fm] = *(const s8v*)(Ab + aoff[fm]);
#pragma unroll
    for (int q = 0; q < 10; ++q)  bv[q] = *(const s8v*)(Bb + boff[q]);
#pragma unroll
    for (int g = 0; g < 5; ++g)
#pragma unroll
      for (int fm = 0; fm < 4; ++fm)
#pragma unroll
        for (int fnl = 0; fnl < 2; ++fnl)
          acc[g][fm][fnl] = __builtin_amdgcn_mfma_f32_16x16x32_bf16(
              af[fm], bv[2 * g + fnl], acc[g][fm][fnl], 0, 0, 0);
    if (have) {
      *(s8v*)(lds + nxt * 16384 + adst0) = pack8(x0, x1);
      *(s8v*)(lds + nxt * 16384 + adst1) = pack8(x2, x3);
    }
    __syncthreads();
  }

  // ---------- epilogue: gates. C/D frag: col=llo (hd), row=lhi*4+reg ----------
  float bb[5][2];
#pragma unroll
  for (int g = 0; g < 5; ++g)
#pragma unroll
    for (int fnl = 0; fnl < 2; ++fnl)
      bb[g][fnl] = p.bias[g][ht * 64 + wc * 32 + fnl * 16 + llo];

#pragma unroll
  for (int fm = 0; fm < 4; ++fm) {
#pragma unroll
    for (int jj = 0; jj < 4; ++jj) {
      int m = bm * 256 + wr * 64 + fm * 16 + lhi * 4 + jj;
      if (m < M) {
        int b = m >> LOGNK, j = m & (NK - 1);
        int nlm = (NL - (NL >> (LEVEL - 1))) + j;
        int colout = (((j + 1) << LEVEL) - 2 - __popc(j)) + 1;
        float* hrow = p.out + ((size_t)b * NMAX + colout) * NH;
        unsigned short* crow = p.cws + ((size_t)b * 255 + nlm) * NH;
        const unsigned short *clrow = nullptr, *crrow = nullptr;
        if constexpr (LEVEL > 1) {
          int offc = NL - (NL >> (LEVEL - 2));
          clrow = p.cws + ((size_t)b * 255 + offc + 2 * j) * NH;
          crrow = p.cws + ((size_t)b * 255 + offc + 2 * j + 1) * NH;
        }
#pragma unroll
        for (int fnl = 0; fnl < 2; ++fnl) {
          int hd = ht * 64 + wc * 32 + fnl * 16 + llo;
          float zi  = acc[0][fm][fnl][jj] + bb[0][fnl];
          float zfl = acc[1][fm][fnl][jj] + bb[1][fnl];
          float zfr = acc[2][fm][fnl][jj] + bb[2][fnl];
          float zo  = acc[3][fm][fnl][jj] + bb[3][fnl];
          float zc  = acc[4][fm][fnl][jj] + bb[4][fnl];
          float cl = 0.5f, cr = 0.5f;
          if constexpr (LEVEL > 1) { cl = bf2f(clrow[hd]); cr = bf2f(crrow[hd]); }
          float cnew = sigf(zi) * tanhf(zc) + sigf(zfl) * cl + sigf(zfr) * cr;
          float hnew = sigf(zo) * tanhf(cnew);
          hrow[hd] = hnew;
          crow[hd] = f2bf(cnew);
          if (LEVEL == 1 && j == 0) p.out[(size_t)b * NMAX * NH + hd] = hnew;
          if constexpr (LEVEL == 8) { p.fh[b * NH + hd] = hnew; p.fc[b * NH + hd] = cnew; }
        }
      }
    }
  }
}

extern "C" void kernel_launch(void* const* d_in, const int* in_sizes, int n_in,
                              void* d_out, int out_size, void* d_ws, size_t ws_size,
                              hipStream_t stream) {
  PrepParams pp;
  for (int i = 0; i < 10; ++i) pp.src[i] = (const float*)d_in[2 + i];
  pp.dst = (unsigned short*)d_ws;

  Params p;
  p.widx = (const int*)d_in[0];
  p.emb  = (const float*)d_in[1];
  for (int g = 0; g < 5; ++g) p.bias[g] = (const float*)d_in[12 + g];
  p.wbf  = (const unsigned short*)d_ws;
  p.out  = (float*)d_out;
  p.fh   = p.out + (size_t)NB * NMAX * NH;
  p.fc   = p.fh + NB * NH;
  p.cws  = (unsigned short*)d_ws + (size_t)10 * NH * NH;  // after bf16 weights

  prep_weights<<<dim3(1280), dim3(256), 0, stream>>>(pp);
  lstm_level<1><<<dim3(64, 8), dim3(512), 0, stream>>>(p);
  lstm_level<2><<<dim3(32, 8), dim3(512), 0, stream>>>(p);
  lstm_level<3><<<dim3(16, 8), dim3(512), 0, stream>>>(p);
  lstm_level<4><<<dim3(8, 8),  dim3(512), 0, stream>>>(p);
  lstm_level<5><<<dim3(4, 8),  dim3(512), 0, stream>>>(p);
  lstm_level<6><<<dim3(2, 8),  dim3(512), 0, stream>>>(p);
  lstm_level<7><<<dim3(1, 8),  dim3(512), 0, stream>>>(p);
  lstm_level<8><<<dim3(1, 8),  dim3(512), 0, stream>>>(p);
}

// Round 4
// 502.539 us; speedup vs baseline: 3.3135x; 1.3288x over previous
//
#include <hip/hip_runtime.h>

#define NB 128
#define NL 256
#define NH 512
#define NMAX 256

typedef __attribute__((ext_vector_type(8))) short s8v;
typedef __attribute__((ext_vector_type(4))) float f4v;

struct Params {
  const int* widx;                 // (B, L) int32
  const float* emb;                // (VOCAB, H) f32
  const float* bias[5];            // each (H,) f32: i, fl, fr, o, c
  const unsigned short* wbf;       // ws: 10 x (H,H) bf16, order [gate][side]
  float* out;                      // (B, 256, H) f32
  float* fh;                       // (B, H) forest_h
  float* fc;                       // (B, H) forest_c
  unsigned short* cws;             // ws: (B, 255, H) bf16 internal-node c
};

struct PrepParams {
  const float* src[10];
  unsigned short* dst;
};

__device__ __forceinline__ float bf2f(unsigned short u) {
  union { unsigned int i; float f; } v;
  v.i = ((unsigned int)u) << 16;
  return v.f;
}
__device__ __forceinline__ unsigned short f2bf(float f) {
  union { float f; unsigned int i; } v;
  v.f = f;
  unsigned int x = v.i;
  x += 0x7fffu + ((x >> 16) & 1u);   // RNE
  return (unsigned short)(x >> 16);
}
__device__ __forceinline__ s8v pack8(f4v a, f4v b) {
  s8v r;
  r[0] = (short)f2bf(a[0]); r[1] = (short)f2bf(a[1]);
  r[2] = (short)f2bf(a[2]); r[3] = (short)f2bf(a[3]);
  r[4] = (short)f2bf(b[0]); r[5] = (short)f2bf(b[1]);
  r[6] = (short)f2bf(b[2]); r[7] = (short)f2bf(b[3]);
  return r;
}
__device__ __forceinline__ float sigf(float x) {
  return 1.f / (1.f + __expf(-x));
}
__device__ __forceinline__ void glds16(const void* g, void* l) {
  __builtin_amdgcn_global_load_lds(
      (const __attribute__((address_space(1))) unsigned int*)g,
      (__attribute__((address_space(3))) unsigned int*)l, 16, 0, 0);
}

// Convert the 10 (H,H) f32 weight matrices to bf16 in ws.
__global__ __launch_bounds__(256) void prep_weights(PrepParams pp) {
  int gid = blockIdx.x * 256 + threadIdx.x;
  int mat = gid >> 15;
  int off = (gid & 32767) * 8;
  const float* s = pp.src[mat] + off;
  f4v x0 = *(const f4v*)s;
  f4v x1 = *(const f4v*)(s + 4);
  *(s8v*)(pp.dst + (size_t)mat * NH * NH + off) = pack8(x0, x1);
}

// Post-order position of internal node (k, j): pos = (j+1)*2^k - 2 - popcount(j).
// Output column = pos + 1 (column 0 duplicates node (1,0)).
//
// Block: BM=128 rows x (5 gates x 64 hd) x K=1024.  640 threads = 10 waves;
// wave (g, mh) computes 64 rows x 64 hd of gate g -> acc[4][4] = 64 VGPR.
// LDS: A[2][128][64B] @0 (16KB), B[2][320][64B] @16384 (40KB).  swz: chunk ^= (row>>1)&3.
// Epilogue: 2 rounds of z-exchange (bf16, 40KB) + all-thread gate math.

template<int LEVEL>
__global__ __launch_bounds__(640, 3)
void lstm_level(Params p) {
  constexpr int NK = NL >> LEVEL;
  constexpr int LOGNK = 8 - LEVEL;
  __shared__ __align__(16) unsigned char lds[57344];

  const int tid = threadIdx.x;
  const int wid = tid >> 6;
  const int lane = tid & 63;
  const int lhi = lane >> 4, llo = lane & 15;
  const int gw = wid >> 1, mh = wid & 1;      // wave = (gate gw, m-half mh)
  const int bm = blockIdx.x, ht = blockIdx.y;

  // ---------- A staging task (tid<512): row ar, 8-float chunk ack ----------
  const int ar = (tid >> 2) & 127, ack = tid & 3;
  const float *aL, *aR;
  {
    int am = bm * 128 + ar;
    int b = am >> LOGNK, j = am & (NK - 1);
    if constexpr (LEVEL == 1) {
      aL = p.emb + (size_t)p.widx[b * NL + 2 * j] * NH;
      aR = p.emb + (size_t)p.widx[b * NL + 2 * j + 1] * NH;
    } else {
      int cl = (((2 * j + 1) << (LEVEL - 1)) - 2 - __popc(j)) + 1;
      int cr = (((2 * j + 2) << (LEVEL - 1)) - 2 - (__popc(j) + 1)) + 1;
      aL = p.out + ((size_t)b * NMAX + cl) * NH;
      aR = p.out + ((size_t)b * NMAX + cr) * NH;
    }
  }
  const int adst = ar * 64 + ((ack ^ ((ar >> 1) & 3)) << 4);

  // ---------- fragment LDS byte offsets (swizzled reads) ----------
  int aoff[4], boff[4];
#pragma unroll
  for (int fm = 0; fm < 4; ++fm) {
    int r = mh * 64 + fm * 16 + llo;
    aoff[fm] = r * 64 + ((lhi ^ ((r >> 1) & 3)) << 4);
  }
#pragma unroll
  for (int fn = 0; fn < 4; ++fn) {
    int r = gw * 64 + fn * 16 + llo;
    boff[fn] = r * 64 + ((lhi ^ ((r >> 1) & 3)) << 4);
  }

  // ---------- B staging: global_load_lds, pre-swizzled global source ----------
  auto stageB = [&](int buf, int tt) {
    const int half = tt >> 4, kk = tt & 15;
#pragma unroll
    for (int ii = 0; ii < 2; ++ii) {
      int i = wid + ii * 10;                      // 20 groups of 16 rows
      int gg = i >> 2;
      int r = i * 16 + (lane >> 2);               // B tile row 0..319
      int ck = (lane & 3) ^ ((r >> 1) & 3);
      const unsigned short* src = p.wbf
          + ((size_t)(2 * gg + half) * NH + (size_t)(ht * 64 + (r & 63))) * NH
          + kk * 32 + ck * 8;
      glds16(src, lds + 16384 + buf * 20480 + i * 1024);
    }
  };

  f4v acc[4][4];
#pragma unroll
  for (int fm = 0; fm < 4; ++fm)
#pragma unroll
    for (int fn = 0; fn < 4; ++fn)
      acc[fm][fn] = (f4v){0.f, 0.f, 0.f, 0.f};

  // ---------- prologue ----------
  f4v x0, x1;
  if (tid < 512) {
    const float* s = aL + ack * 8;
    x0 = *(const f4v*)s; x1 = *(const f4v*)(s + 4);
  }
  stageB(0, 0);
  if (tid < 512) *(s8v*)(lds + adst) = pack8(x0, x1);
  __syncthreads();

  // ---------- main K loop: 32 steps of BK=32 (16 left-child, 16 right) ----------
  for (int t = 0; t < 32; ++t) {
    const int cur = t & 1, nxt = cur ^ 1;
    const bool have = (t + 1) < 32;
    if (have) {
      if (tid < 512) {
        const float* s = ((t + 1) < 16 ? aL : aR) + ((t + 1) & 15) * 32 + ack * 8;
        x0 = *(const f4v*)s; x1 = *(const f4v*)(s + 4);
      }
      stageB(nxt, t + 1);
    }
    const unsigned char* Ab = lds + cur * 8192;
    const unsigned char* Bb = lds + 16384 + cur * 20480;
    s8v af[4], bv[4];
#pragma unroll
    for (int fm = 0; fm < 4; ++fm) af[fm] = *(const s8v*)(Ab + aoff[fm]);
#pragma unroll
    for (int fn = 0; fn < 4; ++fn) bv[fn] = *(const s8v*)(Bb + boff[fn]);
#pragma unroll
    for (int fm = 0; fm < 4; ++fm)
#pragma unroll
      for (int fn = 0; fn < 4; ++fn)
        acc[fm][fn] = __builtin_amdgcn_mfma_f32_16x16x32_bf16(
            af[fm], bv[fn], acc[fm][fn], 0, 0, 0);
    if (have && tid < 512) *(s8v*)(lds + nxt * 8192 + adst) = pack8(x0, x1);
    __syncthreads();
  }

  // ---------- epilogue: 2 rounds of z-exchange + gate math ----------
  // zex layout (bf16): lds[g*8192 + lr*128 + hdl*2], lr in [0,64), hdl in [0,64)
#pragma unroll
  for (int r = 0; r < 2; ++r) {
    if (r == 1) __syncthreads();                  // protect round-0 readers
    if (mh == r) {
#pragma unroll
      for (int fm = 0; fm < 4; ++fm)
#pragma unroll
        for (int fn = 0; fn < 4; ++fn)
#pragma unroll
          for (int jj = 0; jj < 4; ++jj) {
            int lr = fm * 16 + lhi * 4 + jj;      // C/D: row=lhi*4+reg, col=llo
            int cc = fn * 16 + llo;
            *(unsigned short*)(lds + gw * 8192 + lr * 128 + cc * 2) =
                f2bf(acc[fm][fn][jj]);
          }
    }
    __syncthreads();
    for (int idx = tid; idx < 4096; idx += 640) {
      int lr = idx >> 6, hdl = idx & 63;
      int m = bm * 128 + r * 64 + lr;
      int b = m >> LOGNK, j = m & (NK - 1);
      int hd = ht * 64 + hdl;
      float z[5];
#pragma unroll
      for (int g2 = 0; g2 < 5; ++g2)
        z[g2] = bf2f(*(const unsigned short*)(lds + g2 * 8192 + lr * 128 + hdl * 2))
              + p.bias[g2][hd];
      float cl = 0.5f, cr = 0.5f;
      if constexpr (LEVEL > 1) {
        int offc = NL - (NL >> (LEVEL - 2));      // OFF[LEVEL-1]
        cl = bf2f(p.cws[((size_t)b * 255 + offc + 2 * j) * NH + hd]);
        cr = bf2f(p.cws[((size_t)b * 255 + offc + 2 * j + 1) * NH + hd]);
      }
      float cnew = sigf(z[0]) * tanhf(z[4]) + sigf(z[1]) * cl + sigf(z[2]) * cr;
      float hnew = sigf(z[3]) * tanhf(cnew);
      int nlm = (NL - (NL >> (LEVEL - 1))) + j;
      int colout = (((j + 1) << LEVEL) - 2 - __popc(j)) + 1;
      p.out[((size_t)b * NMAX + colout) * NH + hd] = hnew;
      p.cws[((size_t)b * 255 + nlm) * NH + hd] = f2bf(cnew);
      if (LEVEL == 1 && j == 0) p.out[(size_t)b * NMAX * NH + hd] = hnew;
      if constexpr (LEVEL == 8) { p.fh[b * NH + hd] = hnew; p.fc[b * NH + hd] = cnew; }
    }
  }
}

extern "C" void kernel_launch(void* const* d_in, const int* in_sizes, int n_in,
                              void* d_out, int out_size, void* d_ws, size_t ws_size,
                              hipStream_t stream) {
  PrepParams pp;
  for (int i = 0; i < 10; ++i) pp.src[i] = (const float*)d_in[2 + i];
  pp.dst = (unsigned short*)d_ws;

  Params p;
  p.widx = (const int*)d_in[0];
  p.emb  = (const float*)d_in[1];
  for (int g = 0; g < 5; ++g) p.bias[g] = (const float*)d_in[12 + g];
  p.wbf  = (const unsigned short*)d_ws;
  p.out  = (float*)d_out;
  p.fh   = p.out + (size_t)NB * NMAX * NH;
  p.fc   = p.fh + NB * NH;
  p.cws  = (unsigned short*)d_ws + (size_t)10 * NH * NH;  // after bf16 weights

  prep_weights<<<dim3(1280), dim3(256), 0, stream>>>(pp);
  lstm_level<1><<<dim3(128, 8), dim3(640), 0, stream>>>(p);
  lstm_level<2><<<dim3(64, 8),  dim3(640), 0, stream>>>(p);
  lstm_level<3><<<dim3(32, 8),  dim3(640), 0, stream>>>(p);
  lstm_level<4><<<dim3(16, 8),  dim3(640), 0, stream>>>(p);
  lstm_level<5><<<dim3(8, 8),   dim3(640), 0, stream>>>(p);
  lstm_level<6><<<dim3(4, 8),   dim3(640), 0, stream>>>(p);
  lstm_level<7><<<dim3(2, 8),   dim3(640), 0, stream>>>(p);
  lstm_level<8><<<dim3(1, 8),   dim3(640), 0, stream>>>(p);
}

// Round 5
// 458.006 us; speedup vs baseline: 3.6357x; 1.0972x over previous
//
#include <hip/hip_runtime.h>

#define NB 128
#define NL 256
#define NH 512
#define NMAX 256

typedef __attribute__((ext_vector_type(8))) short s8v;
typedef __attribute__((ext_vector_type(4))) float f4v;

struct Params {
  const int* widx;                 // (B, L) int32
  const float* bias[5];            // each (H,) f32: i, fl, fr, o, c
  const unsigned short* wbf;       // ws: 10 x (H,H) bf16, order [gate][side]
  const unsigned short* embbf;     // ws: (VOCAB, H) bf16 (valid during level 1)
  const unsigned short* hcprev;    // prev level: row (b*NKp + node)*2H, h@0 c@H
  unsigned short* hcout;           // this level: row (b*NK + node)*2H
  float* out;                      // (B, 256, H) f32
  float* fh;                       // (B, H)
  float* fc;                       // (B, H)
};

struct PrepParams {
  const float* u[10];
  const float* emb;
  unsigned short* wdst;
  unsigned short* edst;
};

__device__ __forceinline__ float bf2f(unsigned short u) {
  union { unsigned int i; float f; } v;
  v.i = ((unsigned int)u) << 16;
  return v.f;
}
__device__ __forceinline__ unsigned short f2bf(float f) {
  union { float f; unsigned int i; } v;
  v.f = f;
  unsigned int x = v.i;
  x += 0x7fffu + ((x >> 16) & 1u);   // RNE
  return (unsigned short)(x >> 16);
}
__device__ __forceinline__ s8v pack8(f4v a, f4v b) {
  s8v r;
  r[0] = (short)f2bf(a[0]); r[1] = (short)f2bf(a[1]);
  r[2] = (short)f2bf(a[2]); r[3] = (short)f2bf(a[3]);
  r[4] = (short)f2bf(b[0]); r[5] = (short)f2bf(b[1]);
  r[6] = (short)f2bf(b[2]); r[7] = (short)f2bf(b[3]);
  return r;
}
__device__ __forceinline__ float sigf(float x) {
  return 1.f / (1.f + __expf(-x));
}
__device__ __forceinline__ void glds16(const void* g, void* l) {
  __builtin_amdgcn_global_load_lds(
      (const __attribute__((address_space(1))) unsigned int*)g,
      (__attribute__((address_space(3))) unsigned int*)l, 16, 0, 0);
}

// One prep pass: 10 (H,H) weights + the full emb table, f32 -> bf16.
// weights: 10*512*512/8 = 327680 chunks; emb: 32000*512/8 = 2048000 chunks.
__global__ __launch_bounds__(256) void prep_cvt(PrepParams pp) {
  int gid = blockIdx.x * 256 + threadIdx.x;
  const float* s;
  unsigned short* d;
  if (gid < 327680) {
    int mat = gid >> 15, off = (gid & 32767) * 8;
    s = pp.u[mat] + off;
    d = pp.wdst + (size_t)mat * NH * NH + off;
  } else {
    size_t off = (size_t)(gid - 327680) * 8;
    s = pp.emb + off;
    d = pp.edst + off;
  }
  f4v x0 = *(const f4v*)s;
  f4v x1 = *(const f4v*)(s + 4);
  *(s8v*)d = pack8(x0, x1);
}

// Post-order position of internal node (k, j): pos = (j+1)*2^k - 2 - popcount(j).
// Output column = pos + 1 (column 0 duplicates node (1,0)).
//
// Block: BM=128 rows x (5 gates x 64 hd) x K=1024.  640 threads = 10 waves;
// wave (gw, mh) computes 64 rows x 64 hd of gate gw -> acc[4][4].
// LDS: A[2][128][64B] @0 (16KB), B[2][320][64B] @16384 (40KB). swz: chunk ^= (row>>1)&3.
// ALL staging via global_load_lds (A and B), pre-swizzled global sources.
// Epilogue: 2 rounds of z-exchange (bf16, 136B row stride) + all-thread gate math.

template<int LEVEL>
__global__ __launch_bounds__(640, 3)
void lstm_level(Params p) {
  constexpr int NK = NL >> LEVEL;
  constexpr int LOGNK = 8 - LEVEL;
  constexpr int NKP = NL >> (LEVEL - 1);
  __shared__ __align__(16) unsigned char lds[57344];

  const int tid = threadIdx.x;
  const int wid = tid >> 6;
  const int lane = tid & 63;
  const int lhi = lane >> 4, llo = lane & 15;
  const int gw = wid >> 1, mh = wid & 1;      // wave = (gate gw, m-half mh)
  const int bm = blockIdx.x, ht = blockIdx.y;

  // ---------- A staging sources: waves 0..7, thread -> (row ar, chunk ack) ----------
  const int ar = (tid >> 2) & 127, ack = tid & 3;
  const int ck = ack ^ ((ar >> 1) & 3);       // pre-swizzled source chunk
  const unsigned short *aLs, *aRs;
  {
    int am = bm * 128 + ar;
    int b = am >> LOGNK, j = am & (NK - 1);
    if constexpr (LEVEL == 1) {
      aLs = p.embbf + (size_t)p.widx[b * NL + 2 * j] * NH + ck * 8;
      aRs = p.embbf + (size_t)p.widx[b * NL + 2 * j + 1] * NH + ck * 8;
    } else {
      const unsigned short* base = p.hcprev + ((size_t)b * NKP + 2 * j) * (2 * NH);
      aLs = base + ck * 8;                    // left child h
      aRs = base + 2 * NH + ck * 8;           // right child h
    }
  }

  // ---------- fragment LDS byte offsets (swizzled reads) ----------
  int aoff[4], boff[4];
#pragma unroll
  for (int fm = 0; fm < 4; ++fm) {
    int r = mh * 64 + fm * 16 + llo;
    aoff[fm] = r * 64 + ((lhi ^ ((r >> 1) & 3)) << 4);
  }
#pragma unroll
  for (int fn = 0; fn < 4; ++fn) {
    int r = gw * 64 + fn * 16 + llo;
    boff[fn] = r * 64 + ((lhi ^ ((r >> 1) & 3)) << 4);
  }

  // ---------- staging lambdas (all global_load_lds) ----------
  auto stageA = [&](int buf, int tt) {
    if (wid < 8) {
      const unsigned short* src = (tt < 16 ? aLs : aRs) + (tt & 15) * 32;
      glds16(src, lds + buf * 8192 + wid * 1024);
    }
  };
  auto stageB = [&](int buf, int tt) {
    const int half = tt >> 4, kk = tt & 15;
#pragma unroll
    for (int ii = 0; ii < 2; ++ii) {
      int i = wid + ii * 10;                  // 20 groups of 16 rows
      int gg = i >> 2;
      int r = i * 16 + (lane >> 2);           // B tile row 0..319
      int c2 = (lane & 3) ^ ((r >> 1) & 3);
      const unsigned short* src = p.wbf
          + ((size_t)(2 * gg + half) * NH + (size_t)(ht * 64 + (r & 63))) * NH
          + kk * 32 + c2 * 8;
      glds16(src, lds + 16384 + buf * 20480 + i * 1024);
    }
  };

  f4v acc[4][4];
#pragma unroll
  for (int fm = 0; fm < 4; ++fm)
#pragma unroll
    for (int fn = 0; fn < 4; ++fn)
      acc[fm][fn] = (f4v){0.f, 0.f, 0.f, 0.f};

  // ---------- prologue ----------
  stageA(0, 0);
  stageB(0, 0);
  __syncthreads();

  // ---------- main K loop: 32 steps of BK=32 (16 left half, 16 right) ----------
  for (int t = 0; t < 32; ++t) {
    const int cur = t & 1, nxt = cur ^ 1;
    if (t + 1 < 32) {
      stageA(nxt, t + 1);
      stageB(nxt, t + 1);
    }
    const unsigned char* Ab = lds + cur * 8192;
    const unsigned char* Bb = lds + 16384 + cur * 20480;
    s8v af[4], bv[4];
#pragma unroll
    for (int fm = 0; fm < 4; ++fm) af[fm] = *(const s8v*)(Ab + aoff[fm]);
#pragma unroll
    for (int fn = 0; fn < 4; ++fn) bv[fn] = *(const s8v*)(Bb + boff[fn]);
#pragma unroll
    for (int fm = 0; fm < 4; ++fm)
#pragma unroll
      for (int fn = 0; fn < 4; ++fn)
        acc[fm][fn] = __builtin_amdgcn_mfma_f32_16x16x32_bf16(
            af[fm], bv[fn], acc[fm][fn], 0, 0, 0);
    __syncthreads();
  }

  // ---------- epilogue: 2 rounds of z-exchange + gate math ----------
  // zex layout (bf16): lds[g*8704 + lr*136 + hdl*2], lr in [0,64), hdl in [0,64)
#pragma unroll
  for (int r = 0; r < 2; ++r) {
    if (r == 1) __syncthreads();
    if (mh == r) {
#pragma unroll
      for (int fm = 0; fm < 4; ++fm)
#pragma unroll
        for (int fn = 0; fn < 4; ++fn)
#pragma unroll
          for (int jj = 0; jj < 4; ++jj) {
            int lr = fm * 16 + lhi * 4 + jj;  // C/D: row=lhi*4+reg, col=llo
            int cc = fn * 16 + llo;
            *(unsigned short*)(lds + gw * 8704 + lr * 136 + cc * 2) =
                f2bf(acc[fm][fn][jj]);
          }
    }
    __syncthreads();
    for (int idx = tid; idx < 4096; idx += 640) {
      int lr = idx >> 6, hdl = idx & 63;
      int m = bm * 128 + r * 64 + lr;
      int b = m >> LOGNK, j = m & (NK - 1);
      int hd = ht * 64 + hdl;
      float z[5];
#pragma unroll
      for (int g2 = 0; g2 < 5; ++g2)
        z[g2] = bf2f(*(const unsigned short*)(lds + g2 * 8704 + lr * 136 + hdl * 2))
              + p.bias[g2][hd];
      float cl = 0.5f, cr = 0.5f;
      if constexpr (LEVEL > 1) {
        const unsigned short* cb = p.hcprev + ((size_t)b * NKP + 2 * j) * (2 * NH) + NH;
        cl = bf2f(cb[hd]);
        cr = bf2f(cb[2 * NH + hd]);
      }
      float cnew = sigf(z[0]) * tanhf(z[4]) + sigf(z[1]) * cl + sigf(z[2]) * cr;
      float hnew = sigf(z[3]) * tanhf(cnew);
      unsigned short* orow = p.hcout + ((size_t)b * NK + j) * (2 * NH);
      orow[hd] = f2bf(hnew);
      orow[NH + hd] = f2bf(cnew);
      int colout = (((j + 1) << LEVEL) - 2 - __popc(j)) + 1;
      p.out[((size_t)b * NMAX + colout) * NH + hd] = hnew;
      if (LEVEL == 1 && j == 0) p.out[(size_t)b * NMAX * NH + hd] = hnew;
      if constexpr (LEVEL == 8) { p.fh[b * NH + hd] = hnew; p.fc[b * NH + hd] = cnew; }
    }
  }
}

extern "C" void kernel_launch(void* const* d_in, const int* in_sizes, int n_in,
                              void* d_out, int out_size, void* d_ws, size_t ws_size,
                              hipStream_t stream) {
  unsigned short* wbf = (unsigned short*)d_ws;            // 2,621,440 elems (5.24 MB)
  unsigned short* R1  = wbf + (size_t)10 * NH * NH;       // 16,777,216 elems (33.55 MB)
  unsigned short* R2  = R1 + 16777216;                    // 16,777,216 elems (33.55 MB)
  // R1 holds embbf for level 1, then outputs of levels 2,4,6,8.
  // R2 holds outputs of levels 1,3,5,7.  Total ws use: 72.35 MB.

  PrepParams pp;
  for (int i = 0; i < 10; ++i) pp.u[i] = (const float*)d_in[2 + i];
  pp.emb  = (const float*)d_in[1];
  pp.wdst = wbf;
  pp.edst = R1;

  Params p;
  p.widx = (const int*)d_in[0];
  for (int g = 0; g < 5; ++g) p.bias[g] = (const float*)d_in[12 + g];
  p.wbf   = wbf;
  p.embbf = R1;
  p.out   = (float*)d_out;
  p.fh    = p.out + (size_t)NB * NMAX * NH;
  p.fc    = p.fh + NB * NH;

  prep_cvt<<<dim3(9280), dim3(256), 0, stream>>>(pp);

  unsigned short* lvlout[9];
  for (int k = 1; k <= 8; ++k) lvlout[k] = (k & 1) ? R2 : R1;

  p.hcprev = nullptr;     p.hcout = lvlout[1];
  lstm_level<1><<<dim3(128, 8), dim3(640), 0, stream>>>(p);
  p.hcprev = lvlout[1];   p.hcout = lvlout[2];
  lstm_level<2><<<dim3(64, 8),  dim3(640), 0, stream>>>(p);
  p.hcprev = lvlout[2];   p.hcout = lvlout[3];
  lstm_level<3><<<dim3(32, 8),  dim3(640), 0, stream>>>(p);
  p.hcprev = lvlout[3];   p.hcout = lvlout[4];
  lstm_level<4><<<dim3(16, 8),  dim3(640), 0, stream>>>(p);
  p.hcprev = lvlout[4];   p.hcout = lvlout[5];
  lstm_level<5><<<dim3(8, 8),   dim3(640), 0, stream>>>(p);
  p.hcprev = lvlout[5];   p.hcout = lvlout[6];
  lstm_level<6><<<dim3(4, 8),   dim3(640), 0, stream>>>(p);
  p.hcprev = lvlout[6];   p.hcout = lvlout[7];
  lstm_level<7><<<dim3(2, 8),   dim3(640), 0, stream>>>(p);
  p.hcprev = lvlout[7];   p.hcout = lvlout[8];
  lstm_level<8><<<dim3(1, 8),   dim3(640), 0, stream>>>(p);
}

// Round 6
// 441.239 us; speedup vs baseline: 3.7738x; 1.0380x over previous
//
#include <hip/hip_runtime.h>

#define NB 128
#define NL 256
#define NH 512
#define NMAX 256

typedef __attribute__((ext_vector_type(8))) short s8v;
typedef __attribute__((ext_vector_type(4))) float f4v;

struct Params {
  const int* widx;                 // (B, L) int32
  const float* bias[5];            // each (H,) f32: i, fl, fr, o, c
  const unsigned short* wbf;       // ws: 10 x (H,H) bf16, order [gate][side]
  const unsigned short* embbf;     // ws: (VOCAB, H) bf16 (valid during level 1)
  const unsigned short* hcprev;    // prev level: row (b*NKp + node)*2H, h@0 c@H
  unsigned short* hcout;           // this level: row (b*NK + node)*2H
  float* out;                      // (B, 256, H) f32
  float* fh;                       // (B, H)
  float* fc;                       // (B, H)
};

struct PrepParams {
  const float* u[10];
  const float* emb;
  unsigned short* wdst;
  unsigned short* edst;
};

__device__ __forceinline__ float bf2f(unsigned short u) {
  union { unsigned int i; float f; } v;
  v.i = ((unsigned int)u) << 16;
  return v.f;
}
__device__ __forceinline__ unsigned short f2bf(float f) {
  union { float f; unsigned int i; } v;
  v.f = f;
  unsigned int x = v.i;
  x += 0x7fffu + ((x >> 16) & 1u);   // RNE
  return (unsigned short)(x >> 16);
}
__device__ __forceinline__ s8v pack8(f4v a, f4v b) {
  s8v r;
  r[0] = (short)f2bf(a[0]); r[1] = (short)f2bf(a[1]);
  r[2] = (short)f2bf(a[2]); r[3] = (short)f2bf(a[3]);
  r[4] = (short)f2bf(b[0]); r[5] = (short)f2bf(b[1]);
  r[6] = (short)f2bf(b[2]); r[7] = (short)f2bf(b[3]);
  return r;
}
__device__ __forceinline__ float sigf(float x) {
  return 1.f / (1.f + __expf(-x));
}
__device__ __forceinline__ void glds16(const void* g, void* l) {
  __builtin_amdgcn_global_load_lds(
      (const __attribute__((address_space(1))) unsigned int*)g,
      (__attribute__((address_space(3))) unsigned int*)l, 16, 0, 0);
}
__device__ __forceinline__ void barrier_raw() {
  __builtin_amdgcn_sched_barrier(0);
  __builtin_amdgcn_s_barrier();
  __builtin_amdgcn_sched_barrier(0);
}
#define WAITV(N) do { asm volatile("s_waitcnt vmcnt(" #N ")" ::: "memory"); \
                      __builtin_amdgcn_sched_barrier(0); } while (0)

// One prep pass: 10 (H,H) weights + the full emb table, f32 -> bf16.
__global__ __launch_bounds__(256) void prep_cvt(PrepParams pp) {
  int gid = blockIdx.x * 256 + threadIdx.x;
  const float* s;
  unsigned short* d;
  if (gid < 327680) {
    int mat = gid >> 15, off = (gid & 32767) * 8;
    s = pp.u[mat] + off;
    d = pp.wdst + (size_t)mat * NH * NH + off;
  } else {
    size_t off = (size_t)(gid - 327680) * 8;
    s = pp.emb + off;
    d = pp.edst + off;
  }
  f4v x0 = *(const f4v*)s;
  f4v x1 = *(const f4v*)(s + 4);
  *(s8v*)d = pack8(x0, x1);
}

// Post-order position of internal node (k, j): pos = (j+1)*2^k - 2 - popcount(j).
// Output column = pos + 1 (column 0 duplicates node (1,0)).
//
// Block: BM=128 rows x (5 gates x 64 hd) x K=1024.  640 threads = 10 waves;
// wave (gw, mh) computes 64 rows x 64 hd of gate gw -> acc[4][4].
// LDS: A[4][128][64B] @0 (32KB), B[4][320][64B] @32768 (80KB). swz: chunk ^= (row>>1)&3.
// Pipeline: prefetch depth 3, counted vmcnt (per-wave 3 loads/tile for waves 0-7,
// 2 for waves 8-9), raw s_barrier. Never drains vmcnt in the main loop.
// Epilogue: 2 rounds of z-exchange (bf16, 136B row stride) + all-thread gate math.

template<int LEVEL>
__global__ __launch_bounds__(640, 2)
void lstm_level(Params p) {
  constexpr int NK = NL >> LEVEL;
  constexpr int LOGNK = 8 - LEVEL;
  constexpr int NKP = NL >> (LEVEL - 1);
  __shared__ __align__(16) unsigned char lds[114688];

  const int tid = threadIdx.x;
  const int wid = tid >> 6;
  const int lane = tid & 63;
  const int lhi = lane >> 4, llo = lane & 15;
  const int gw = wid >> 1, mh = wid & 1;      // wave = (gate gw, m-half mh)
  const int bm = blockIdx.x, ht = blockIdx.y;

  // ---------- A staging sources: waves 0..7, thread -> (row ar, chunk ack) ----------
  const int ar = (tid >> 2) & 127, ack = tid & 3;
  const int ck = ack ^ ((ar >> 1) & 3);       // pre-swizzled source chunk
  const unsigned short *aLs, *aRs;
  {
    int am = bm * 128 + ar;
    int b = am >> LOGNK, j = am & (NK - 1);
    if constexpr (LEVEL == 1) {
      aLs = p.embbf + (size_t)p.widx[b * NL + 2 * j] * NH + ck * 8;
      aRs = p.embbf + (size_t)p.widx[b * NL + 2 * j + 1] * NH + ck * 8;
    } else {
      const unsigned short* base = p.hcprev + ((size_t)b * NKP + 2 * j) * (2 * NH);
      aLs = base + ck * 8;                    // left child h
      aRs = base + 2 * NH + ck * 8;           // right child h
    }
  }

  // ---------- fragment LDS byte offsets (swizzled reads) ----------
  int aoff[4], boff[4];
#pragma unroll
  for (int fm = 0; fm < 4; ++fm) {
    int r = mh * 64 + fm * 16 + llo;
    aoff[fm] = r * 64 + ((lhi ^ ((r >> 1) & 3)) << 4);
  }
#pragma unroll
  for (int fn = 0; fn < 4; ++fn) {
    int r = gw * 64 + fn * 16 + llo;
    boff[fn] = r * 64 + ((lhi ^ ((r >> 1) & 3)) << 4);
  }

  // ---------- staging: all global_load_lds, pre-swizzled global sources ----------
  auto do_stage = [&](int tt) {
    const int buf = tt & 3;
    if (wid < 8) {
      const unsigned short* src = (tt < 16 ? aLs : aRs) + (tt & 15) * 32;
      glds16(src, lds + buf * 8192 + wid * 1024);
    }
    const int half = tt >> 4, kk = tt & 15;
#pragma unroll
    for (int ii = 0; ii < 2; ++ii) {
      int i = wid + ii * 10;                  // 20 groups of 16 rows
      int gg = i >> 2;
      int r = i * 16 + (lane >> 2);           // B tile row 0..319
      int c2 = (lane & 3) ^ ((r >> 1) & 3);
      const unsigned short* src = p.wbf
          + ((size_t)(2 * gg + half) * NH + (size_t)(ht * 64 + (r & 63))) * NH
          + kk * 32 + c2 * 8;
      glds16(src, lds + 32768 + buf * 20480 + i * 1024);
    }
  };

  f4v acc[4][4];
#pragma unroll
  for (int fm = 0; fm < 4; ++fm)
#pragma unroll
    for (int fn = 0; fn < 4; ++fn)
      acc[fm][fn] = (f4v){0.f, 0.f, 0.f, 0.f};

  auto compute = [&](int cur) {
    const unsigned char* Ab = lds + cur * 8192;
    const unsigned char* Bb = lds + 32768 + cur * 20480;
    s8v af[4], bv[4];
#pragma unroll
    for (int fm = 0; fm < 4; ++fm) af[fm] = *(const s8v*)(Ab + aoff[fm]);
#pragma unroll
    for (int fn = 0; fn < 4; ++fn) bv[fn] = *(const s8v*)(Bb + boff[fn]);
    __builtin_amdgcn_s_setprio(1);
#pragma unroll
    for (int fm = 0; fm < 4; ++fm)
#pragma unroll
      for (int fn = 0; fn < 4; ++fn)
        acc[fm][fn] = __builtin_amdgcn_mfma_f32_16x16x32_bf16(
            af[fm], bv[fn], acc[fm][fn], 0, 0, 0);
    __builtin_amdgcn_s_setprio(0);
  };

  // ---------- pipelined K loop: 32 tiles of BK=32, depth-3 prefetch ----------
  do_stage(0);
  do_stage(1);
  do_stage(2);
  for (int t = 0; t < 30; ++t) {
    if (wid < 8) WAITV(6); else WAITV(4);     // tile t landed; t+1,t+2 in flight
    barrier_raw();
    if (t <= 28) do_stage(t + 3);
    compute(t & 3);
  }
  if (wid < 8) WAITV(3); else WAITV(2);       // t=30
  barrier_raw();
  compute(2);
  WAITV(0);                                   // t=31
  barrier_raw();
  compute(3);
  __syncthreads();                            // full drain before LDS reuse

  // ---------- epilogue: 2 rounds of z-exchange + gate math ----------
  // zex layout (bf16): lds[g*8704 + lr*136 + hdl*2], lr in [0,64), hdl in [0,64)
#pragma unroll
  for (int r = 0; r < 2; ++r) {
    if (r == 1) __syncthreads();
    if (mh == r) {
#pragma unroll
      for (int fm = 0; fm < 4; ++fm)
#pragma unroll
        for (int fn = 0; fn < 4; ++fn)
#pragma unroll
          for (int jj = 0; jj < 4; ++jj) {
            int lr = fm * 16 + lhi * 4 + jj;  // C/D: row=lhi*4+reg, col=llo
            int cc = fn * 16 + llo;
            *(unsigned short*)(lds + gw * 8704 + lr * 136 + cc * 2) =
                f2bf(acc[fm][fn][jj]);
          }
    }
    __syncthreads();
    for (int idx = tid; idx < 4096; idx += 640) {
      int lr = idx >> 6, hdl = idx & 63;
      int m = bm * 128 + r * 64 + lr;
      int b = m >> LOGNK, j = m & (NK - 1);
      int hd = ht * 64 + hdl;
      float z[5];
#pragma unroll
      for (int g2 = 0; g2 < 5; ++g2)
        z[g2] = bf2f(*(const unsigned short*)(lds + g2 * 8704 + lr * 136 + hdl * 2))
              + p.bias[g2][hd];
      float cl = 0.5f, cr = 0.5f;
      if constexpr (LEVEL > 1) {
        const unsigned short* cb = p.hcprev + ((size_t)b * NKP + 2 * j) * (2 * NH) + NH;
        cl = bf2f(cb[hd]);
        cr = bf2f(cb[2 * NH + hd]);
      }
      float cnew = sigf(z[0]) * tanhf(z[4]) + sigf(z[1]) * cl + sigf(z[2]) * cr;
      float hnew = sigf(z[3]) * tanhf(cnew);
      unsigned short* orow = p.hcout + ((size_t)b * NK + j) * (2 * NH);
      orow[hd] = f2bf(hnew);
      orow[NH + hd] = f2bf(cnew);
      int colout = (((j + 1) << LEVEL) - 2 - __popc(j)) + 1;
      p.out[((size_t)b * NMAX + colout) * NH + hd] = hnew;
      if (LEVEL == 1 && j == 0) p.out[(size_t)b * NMAX * NH + hd] = hnew;
      if constexpr (LEVEL == 8) { p.fh[b * NH + hd] = hnew; p.fc[b * NH + hd] = cnew; }
    }
  }
}

extern "C" void kernel_launch(void* const* d_in, const int* in_sizes, int n_in,
                              void* d_out, int out_size, void* d_ws, size_t ws_size,
                              hipStream_t stream) {
  unsigned short* wbf = (unsigned short*)d_ws;            // 2,621,440 elems (5.24 MB)
  unsigned short* R1  = wbf + (size_t)10 * NH * NH;       // 16,777,216 elems (33.55 MB)
  unsigned short* R2  = R1 + 16777216;                    // 16,777,216 elems (33.55 MB)
  // R1 holds embbf for level 1, then outputs of levels 2,4,6,8.
  // R2 holds outputs of levels 1,3,5,7.  Total ws use: 72.35 MB.

  PrepParams pp;
  for (int i = 0; i < 10; ++i) pp.u[i] = (const float*)d_in[2 + i];
  pp.emb  = (const float*)d_in[1];
  pp.wdst = wbf;
  pp.edst = R1;

  Params p;
  p.widx = (const int*)d_in[0];
  for (int g = 0; g < 5; ++g) p.bias[g] = (const float*)d_in[12 + g];
  p.wbf   = wbf;
  p.embbf = R1;
  p.out   = (float*)d_out;
  p.fh    = p.out + (size_t)NB * NMAX * NH;
  p.fc    = p.fh + NB * NH;

  prep_cvt<<<dim3(9280), dim3(256), 0, stream>>>(pp);

  unsigned short* lvlout[9];
  for (int k = 1; k <= 8; ++k) lvlout[k] = (k & 1) ? R2 : R1;

  p.hcprev = nullptr;     p.hcout = lvlout[1];
  lstm_level<1><<<dim3(128, 8), dim3(640), 0, stream>>>(p);
  p.hcprev = lvlout[1];   p.hcout = lvlout[2];
  lstm_level<2><<<dim3(64, 8),  dim3(640), 0, stream>>>(p);
  p.hcprev = lvlout[2];   p.hcout = lvlout[3];
  lstm_level<3><<<dim3(32, 8),  dim3(640), 0, stream>>>(p);
  p.hcprev = lvlout[3];   p.hcout = lvlout[4];
  lstm_level<4><<<dim3(16, 8),  dim3(640), 0, stream>>>(p);
  p.hcprev = lvlout[4];   p.hcout = lvlout[5];
  lstm_level<5><<<dim3(8, 8),   dim3(640), 0, stream>>>(p);
  p.hcprev = lvlout[5];   p.hcout = lvlout[6];
  lstm_level<6><<<dim3(4, 8),   dim3(640), 0, stream>>>(p);
  p.hcprev = lvlout[6];   p.hcout = lvlout[7];
  lstm_level<7><<<dim3(2, 8),   dim3(640), 0, stream>>>(p);
  p.hcprev = lvlout[7];   p.hcout = lvlout[8];
  lstm_level<8><<<dim3(1, 8),   dim3(640), 0, stream>>>(p);
}

// Round 7
// 440.072 us; speedup vs baseline: 3.7838x; 1.0027x over previous
//
#include <hip/hip_runtime.h>

#define NB 128
#define NL 256
#define NH 512
#define NMAX 256

typedef __attribute__((ext_vector_type(8))) short s8v;
typedef __attribute__((ext_vector_type(4))) float f4v;

struct Params {
  const int* widx;                 // (B, L) int32
  const float* bias[5];            // each (H,) f32: i, fl, fr, o, c
  const unsigned short* wbf;       // ws: 10 x (H,H) bf16, order [gate][side]
  const unsigned short* embbf;     // ws: (VOCAB, H) bf16 (valid during level 1)
  const unsigned short* hcprev;    // prev level: row (b*NKp + node)*2H, h@0 c@H
  unsigned short* hcout;           // this level: row (b*NK + node)*2H
  float* out;                      // (B, 256, H) f32
  float* fh;                       // (B, H)
  float* fc;                       // (B, H)
};

struct PrepParams {
  const float* u[10];
  const float* emb;
  unsigned short* wdst;
  unsigned short* edst;
};

__device__ __forceinline__ float bf2f(unsigned short u) {
  union { unsigned int i; float f; } v;
  v.i = ((unsigned int)u) << 16;
  return v.f;
}
__device__ __forceinline__ unsigned short f2bf(float f) {
  union { float f; unsigned int i; } v;
  v.f = f;
  unsigned int x = v.i;
  x += 0x7fffu + ((x >> 16) & 1u);   // RNE
  return (unsigned short)(x >> 16);
}
__device__ __forceinline__ s8v pack8(f4v a, f4v b) {
  s8v r;
  r[0] = (short)f2bf(a[0]); r[1] = (short)f2bf(a[1]);
  r[2] = (short)f2bf(a[2]); r[3] = (short)f2bf(a[3]);
  r[4] = (short)f2bf(b[0]); r[5] = (short)f2bf(b[1]);
  r[6] = (short)f2bf(b[2]); r[7] = (short)f2bf(b[3]);
  return r;
}
__device__ __forceinline__ float sigf(float x) {
  return 1.f / (1.f + __expf(-x));
}
__device__ __forceinline__ void glds16(const void* g, void* l) {
  __builtin_amdgcn_global_load_lds(
      (const __attribute__((address_space(1))) unsigned int*)g,
      (__attribute__((address_space(3))) unsigned int*)l, 16, 0, 0);
}

// One prep pass: 10 (H,H) weights + the full emb table, f32 -> bf16.
__global__ __launch_bounds__(256) void prep_cvt(PrepParams pp) {
  int gid = blockIdx.x * 256 + threadIdx.x;
  const float* s;
  unsigned short* d;
  if (gid < 327680) {
    int mat = gid >> 15, off = (gid & 32767) * 8;
    s = pp.u[mat] + off;
    d = pp.wdst + (size_t)mat * NH * NH + off;
  } else {
    size_t off = (size_t)(gid - 327680) * 8;
    s = pp.emb + off;
    d = pp.edst + off;
  }
  f4v x0 = *(const f4v*)s;
  f4v x1 = *(const f4v*)(s + 4);
  *(s8v*)d = pack8(x0, x1);
}

// Post-order position of internal node (k, j): pos = (j+1)*2^k - 2 - popcount(j).
// Output column = pos + 1 (column 0 duplicates node (1,0)).
//
// Block: BM rows x (5 gates x 64 hd) x K=1024.  BM*2 threads = BM/32 waves.
// Wave (mh, q) computes 128 rows x (5 gates x 16 hd): acc[8][5], 13 ds_reads
// per 40 MFMA.  All 5 gates of an output element land in ONE thread ->
// thread-local gate epilogue, no z-exchange.
// LDS per buffer: A[BM][64B] + B[320][64B]; 2 buffers -> 2 blocks/CU.
// XOR swizzle chunk ^= (row>>1)&3 on both sides (verified conflict-free).

template<int LEVEL, int BM>
__global__ __launch_bounds__(BM * 2, 2)
void lstm_level(Params p) {
  constexpr int NK = NL >> LEVEL;
  constexpr int LOGNK = 8 - LEVEL;
  constexpr int NKP = NL >> (LEVEL - 1);
  constexpr int M = NB * NK;
  constexpr int W = BM / 32;                    // waves per block
  constexpr int BUFSZ = BM * 64 + 20480;        // A + B bytes per buffer
  __shared__ __align__(16) unsigned char lds[2 * BUFSZ];

  const int tid = threadIdx.x;
  const int wid = tid >> 6;
  const int lane = tid & 63;
  const int lhi = lane >> 4, llo = lane & 15;
  const int mh = (BM == 256) ? (wid & 1) : 0;   // m-half (128 rows)
  const int q  = (BM == 256) ? (wid >> 1) : wid; // 16-hd slice
  const int bm = blockIdx.x, ht = blockIdx.y;

  const unsigned short* abase = (LEVEL == 1) ? p.embbf : p.hcprev;

  // ---------- A staging: 2 glds/wave; group gi covers rows gi*16..+15 ----------
  int aOffL[2], aOffR[2];
#pragma unroll
  for (int ii = 0; ii < 2; ++ii) {
    int gi = ii * W + wid;
    int ar = gi * 16 + (lane >> 2);
    int ck = (lane & 3) ^ ((ar >> 1) & 3);
    int am = bm * BM + ar; if (am > M - 1) am = M - 1;
    int b = am >> LOGNK, j = am & (NK - 1);
    if constexpr (LEVEL == 1) {
      aOffL[ii] = p.widx[b * NL + 2 * j] * NH + ck * 8;
      aOffR[ii] = p.widx[b * NL + 2 * j + 1] * NH + ck * 8;
    } else {
      int base = (b * NKP + 2 * j) * (2 * NH);
      aOffL[ii] = base + ck * 8;
      aOffR[ii] = base + 2 * NH + ck * 8;
    }
  }

  // ---------- B staging: groups gi of 16 rows; row = gate*64 + hd-in-tile ----------
  constexpr int BI = (20 + W - 1) / W;
  int bOff[BI];
#pragma unroll
  for (int ii = 0; ii < BI; ++ii) {
    int gi = ii * W + wid;
    if (gi < 20) {
      int r = gi * 16 + (lane >> 2);
      int gg = gi >> 2;
      int ck = (lane & 3) ^ ((r >> 1) & 3);
      bOff[ii] = ((2 * gg) * NH + (ht * 64 + (r & 63))) * NH + ck * 8;
    } else bOff[ii] = 0;
  }

  auto do_stage = [&](int buf, int tt) {
    unsigned char* base = lds + buf * BUFSZ;
    const int kw = (tt & 15) * 32;
    const int* ao = (tt < 16) ? aOffL : aOffR;
#pragma unroll
    for (int ii = 0; ii < 2; ++ii)
      glds16(abase + ao[ii] + kw, base + (ii * W + wid) * 1024);
    const size_t wsel = (size_t)(tt >> 4) * NH * NH;
#pragma unroll
    for (int ii = 0; ii < BI; ++ii) {
      int gi = ii * W + wid;
      if (gi < 20)
        glds16(p.wbf + wsel + bOff[ii] + kw, base + BM * 64 + gi * 1024);
    }
  };

  // ---------- fragment LDS byte offsets (swizzled reads) ----------
  int aoff[8], boff[5];
#pragma unroll
  for (int fm = 0; fm < 8; ++fm) {
    int r = mh * 128 + fm * 16 + llo;
    aoff[fm] = r * 64 + ((lhi ^ ((r >> 1) & 3)) << 4);
  }
#pragma unroll
  for (int g = 0; g < 5; ++g) {
    int r = g * 64 + q * 16 + llo;
    boff[g] = BM * 64 + r * 64 + ((lhi ^ ((r >> 1) & 3)) << 4);
  }

  f4v acc[8][5];
#pragma unroll
  for (int fm = 0; fm < 8; ++fm)
#pragma unroll
    for (int g = 0; g < 5; ++g)
      acc[fm][g] = (f4v){0.f, 0.f, 0.f, 0.f};

  auto compute = [&](int buf) {
    const unsigned char* base = lds + buf * BUFSZ;
    s8v af[8], bv[5];
#pragma unroll
    for (int fm = 0; fm < 8; ++fm) af[fm] = *(const s8v*)(base + aoff[fm]);
#pragma unroll
    for (int g = 0; g < 5; ++g)  bv[g] = *(const s8v*)(base + boff[g]);
    __builtin_amdgcn_s_setprio(1);
#pragma unroll
    for (int fm = 0; fm < 8; ++fm)
#pragma unroll
      for (int g = 0; g < 5; ++g)
        acc[fm][g] = __builtin_amdgcn_mfma_f32_16x16x32_bf16(
            af[fm], bv[g], acc[fm][g], 0, 0, 0);
    __builtin_amdgcn_s_setprio(0);
  };

  // ---------- K loop: 32 tiles of BK=32, 2-buffer, 2 blocks/CU overlap ----------
  do_stage(0, 0);
  __syncthreads();
  for (int t = 0; t < 32; ++t) {
    const int cur = t & 1;
    if (t + 1 < 32) do_stage(cur ^ 1, t + 1);
    compute(cur);
    __syncthreads();
  }

  // ---------- epilogue: fully thread-local gate math ----------
  const int hd = ht * 64 + q * 16 + llo;
  float bb[5];
#pragma unroll
  for (int g = 0; g < 5; ++g) bb[g] = p.bias[g][hd];

#pragma unroll
  for (int fm = 0; fm < 8; ++fm) {
#pragma unroll
    for (int jj = 0; jj < 4; ++jj) {
      int m = bm * BM + mh * 128 + fm * 16 + lhi * 4 + jj;
      if (m < M) {
        int b = m >> LOGNK, j = m & (NK - 1);
        float zi  = acc[fm][0][jj] + bb[0];
        float zfl = acc[fm][1][jj] + bb[1];
        float zfr = acc[fm][2][jj] + bb[2];
        float zo  = acc[fm][3][jj] + bb[3];
        float zc  = acc[fm][4][jj] + bb[4];
        float cl = 0.5f, cr = 0.5f;
        if constexpr (LEVEL > 1) {
          const unsigned short* cb =
              p.hcprev + ((size_t)b * NKP + 2 * j) * (2 * NH) + NH;
          cl = bf2f(cb[hd]);
          cr = bf2f(cb[2 * NH + hd]);
        }
        float cnew = sigf(zi) * tanhf(zc) + sigf(zfl) * cl + sigf(zfr) * cr;
        float hnew = sigf(zo) * tanhf(cnew);
        unsigned short* orow = p.hcout + ((size_t)b * NK + j) * (2 * NH);
        orow[hd] = f2bf(hnew);
        orow[NH + hd] = f2bf(cnew);
        int colout = (((j + 1) << LEVEL) - 2 - __popc(j)) + 1;
        p.out[((size_t)b * NMAX + colout) * NH + hd] = hnew;
        if (LEVEL == 1 && j == 0) p.out[(size_t)b * NMAX * NH + hd] = hnew;
        if constexpr (LEVEL == 8) { p.fh[b * NH + hd] = hnew; p.fc[b * NH + hd] = cnew; }
      }
    }
  }
}

extern "C" void kernel_launch(void* const* d_in, const int* in_sizes, int n_in,
                              void* d_out, int out_size, void* d_ws, size_t ws_size,
                              hipStream_t stream) {
  unsigned short* wbf = (unsigned short*)d_ws;            // 2,621,440 elems (5.24 MB)
  unsigned short* R1  = wbf + (size_t)10 * NH * NH;       // 16,777,216 elems (33.55 MB)
  unsigned short* R2  = R1 + 16777216;                    // 16,777,216 elems (33.55 MB)
  // R1 holds embbf for level 1, then outputs of levels 2,4,6,8.
  // R2 holds outputs of levels 1,3,5,7.  Total ws use: 72.35 MB.

  PrepParams pp;
  for (int i = 0; i < 10; ++i) pp.u[i] = (const float*)d_in[2 + i];
  pp.emb  = (const float*)d_in[1];
  pp.wdst = wbf;
  pp.edst = R1;

  Params p;
  p.widx = (const int*)d_in[0];
  for (int g = 0; g < 5; ++g) p.bias[g] = (const float*)d_in[12 + g];
  p.wbf   = wbf;
  p.embbf = R1;
  p.out   = (float*)d_out;
  p.fh    = p.out + (size_t)NB * NMAX * NH;
  p.fc    = p.fh + NB * NH;

  prep_cvt<<<dim3(9280), dim3(256), 0, stream>>>(pp);

  unsigned short* lvlout[9];
  for (int k = 1; k <= 8; ++k) lvlout[k] = (k & 1) ? R2 : R1;

  p.hcprev = nullptr;     p.hcout = lvlout[1];
  lstm_level<1, 256><<<dim3(64, 8), dim3(512), 0, stream>>>(p);
  p.hcprev = lvlout[1];   p.hcout = lvlout[2];
  lstm_level<2, 128><<<dim3(64, 8), dim3(256), 0, stream>>>(p);
  p.hcprev = lvlout[2];   p.hcout = lvlout[3];
  lstm_level<3, 128><<<dim3(32, 8), dim3(256), 0, stream>>>(p);
  p.hcprev = lvlout[3];   p.hcout = lvlout[4];
  lstm_level<4, 128><<<dim3(16, 8), dim3(256), 0, stream>>>(p);
  p.hcprev = lvlout[4];   p.hcout = lvlout[5];
  lstm_level<5, 128><<<dim3(8, 8),  dim3(256), 0, stream>>>(p);
  p.hcprev = lvlout[5];   p.hcout = lvlout[6];
  lstm_level<6, 128><<<dim3(4, 8),  dim3(256), 0, stream>>>(p);
  p.hcprev = lvlout[6];   p.hcout = lvlout[7];
  lstm_level<7, 128><<<dim3(2, 8),  dim3(256), 0, stream>>>(p);
  p.hcprev = lvlout[7];   p.hcout = lvlout[8];
  lstm_level<8, 128><<<dim3(1, 8),  dim3(256), 0, stream>>>(p);
}